// Round 4
// baseline (215.590 us; speedup 1.0000x reference)
//
#include <hip/hip_runtime.h>
#include <math.h>

#define T_DIM 2048
#define B_DIM 2
#define D_DIM 256
#define TC 512
#define KV_LEN 2560   // TC + T

__device__ __forceinline__ float wave_sum64(float v) {
#pragma unroll
    for (int off = 32; off > 0; off >>= 1) v += __shfl_xor(v, off, 64);
    return v;
}

__device__ __forceinline__ float rope_angle(int pos, int j) {
    float inv = powf(10000.0f, -(float)j * (1.0f / 32.0f));
    return (float)pos * inv;
}

// ---------------------------------------------------------------------------
// Phase 1 (fused): blocks [0,256) = proj (16 tokens each), [256,512) =
// compress (4 comp tokens each). 256 threads.
//
// proj: Pre = H @ [W_Q(256) | W_KV(64) | W_DQ(64)]. Wave tg owns tokens
// 4tg..4tg+3; lane l owns col pairs {2l,2l+1}, {128+2l,..}, {256+2l,..}.
// H is staged transposed (sHT[k][tok]) so the inner loop is 1 b128 broadcast
// (4 tokens' h at one k) + 3 b64 W reads + 24 FMA -> VALU-bound.
// acc[tt][2m+p]: m=0 -> heads 0/1 (by half-wave), m=1 -> heads 2/3,
// m=2 -> lanes<32: KV cols, lanes>=32: H_dc cols. Epilogue is wave-local.
// ---------------------------------------------------------------------------
__global__ __launch_bounds__(256) void k_phase1(
    const float* __restrict__ H, const float* __restrict__ W_Q,
    const float* __restrict__ W_KV, const float* __restrict__ W_DQ,
    const float* __restrict__ W_IUQ, const float* __restrict__ W_w,
    const float* __restrict__ Wc_comp, const float* __restrict__ Wc_idx,
    const float* __restrict__ g_q, const float* __restrict__ g_k,
    const float* __restrict__ g_v,
    float* __restrict__ QI, float* __restrict__ Wiw, float* __restrict__ Qr,
    float* __restrict__ KIbuf, float* __restrict__ Kbuf, float* __restrict__ Vbuf)
{
    __shared__ float smem[12544];   // 49 KB
    int tid = threadIdx.x;
    int lane = tid & 63;
    int wv = tid >> 6;

    if (blockIdx.x < 256) {
        // ---------------- proj path ----------------
        int bt0 = blockIdx.x * 16;
        float* sHT = smem;            // [256 k][20] tok-major-transposed: 5120
        float* sW  = smem + 5120;     // [16 k][384]: 6144
        float* sHdc = smem + 11264;   // [16 tok][64]: 1024
        float* sWw = smem + 12288;    // 256

        // stage H transposed: iter = token, thread tid = feature col
        // write bank stride 20 -> 8-way conflict, one-time cost only.
#pragma unroll 4
        for (int it = 0; it < 16; ++it) {
            float v = H[((size_t)(bt0 + it)) * 256 + tid];
            sHT[tid * 20 + it] = v;
        }

        int l = lane, tg = wv;
        float acc[4][6];
#pragma unroll
        for (int a = 0; a < 4; ++a)
#pragma unroll
            for (int m = 0; m < 6; ++m) acc[a][m] = 0.f;

        for (int kc = 0; kc < 16; ++kc) {
            __syncthreads();
            for (int i = tid; i < 1536; i += 256) {
                int r = i / 96;
                int cc = (i % 96) * 4;
                int gr = kc * 16 + r;
                float4 v;
                if (cc < 256)      v = *(const float4*)(W_Q + (size_t)gr * 256 + cc);
                else if (cc < 320) v = *(const float4*)(W_KV + (size_t)gr * 64 + (cc - 256));
                else               v = *(const float4*)(W_DQ + (size_t)gr * 64 + (cc - 320));
                *(float4*)&sW[r * 384 + cc] = v;
            }
            __syncthreads();
#pragma unroll
            for (int k = 0; k < 16; ++k) {
                float4 h4 = *(float4*)&sHT[(kc * 16 + k) * 20 + 4 * tg];
                float2 w0 = *(float2*)&sW[k * 384 + 2 * l];
                float2 w1 = *(float2*)&sW[k * 384 + 128 + 2 * l];
                float2 w2 = *(float2*)&sW[k * 384 + 256 + 2 * l];
                const float* hp = (const float*)&h4;
#pragma unroll
                for (int tt = 0; tt < 4; ++tt) {
                    float h = hp[tt];
                    acc[tt][0] = fmaf(h, w0.x, acc[tt][0]);
                    acc[tt][1] = fmaf(h, w0.y, acc[tt][1]);
                    acc[tt][2] = fmaf(h, w1.x, acc[tt][2]);
                    acc[tt][3] = fmaf(h, w1.y, acc[tt][3]);
                    acc[tt][4] = fmaf(h, w2.x, acc[tt][4]);
                    acc[tt][5] = fmaf(h, w2.y, acc[tt][5]);
                }
            }
        }

        // epilogue (register-local per wave)
        int il = l & 31;
        int half_hi = l >> 5;
#pragma unroll
        for (int tt = 0; tt < 4; ++tt) {
            int tok = 4 * tg + tt;
            int bt = bt0 + tok;
            int b = bt >> 11;
            int t = bt & 2047;
            int j0 = 2 * (il & 15), j1 = j0 + 1;
            float s0, c0, s1, c1;
            sincosf(rope_angle(t, j0), &s0, &c0);
            sincosf(rope_angle(t, j1), &s1, &c1);

            // Q heads (m=0 -> heads 0/1, m=1 -> heads 2/3)
#pragma unroll
            for (int mg = 0; mg < 2; ++mg) {
                int h = mg * 2 + half_hi;
                float a = acc[tt][2 * mg], bb = acc[tt][2 * mg + 1];
                float ss = a * a + bb * bb;
#pragma unroll
                for (int off = 1; off <= 16; off <<= 1) ss += __shfl_xor(ss, off, 64);
                float sc = rsqrtf(ss * (1.0f / 64.0f) + 1e-6f);
                float qa = a * sc * g_q[h * 64 + 2 * il];
                float qb = bb * sc * g_q[h * 64 + 2 * il + 1];
                float pa = __shfl_xor(qa, 16, 64);
                float pb = __shfl_xor(qb, 16, 64);
                float oa, ob;
                if (il < 16) { oa = fmaf(qa, c0, -pa * s0); ob = fmaf(qb, c1, -pb * s1); }
                else         { oa = fmaf(pa, s0, qa * c0);  ob = fmaf(pb, s1, qb * c1); }
                *(float2*)&Qr[(size_t)bt * 256 + h * 64 + 2 * il] = make_float2(oa, ob);
            }

            if (l < 32) {
                // sliding KV (64-dim held 2-per-lane in lanes 0..31)
                float a = acc[tt][4], bb = acc[tt][5];
                float ss = a * a + bb * bb;
#pragma unroll
                for (int off = 1; off <= 16; off <<= 1) ss += __shfl_xor(ss, off, 64);
                float sc = rsqrtf(ss * (1.0f / 64.0f) + 1e-6f);
                float ka = a * sc * g_k[2 * il], kb = bb * sc * g_k[2 * il + 1];
                float va = a * sc * g_v[2 * il], vb = bb * sc * g_v[2 * il + 1];
                int pos = TC + t;
                float s0p, c0p, s1p, c1p;
                sincosf(rope_angle(pos, j0), &s0p, &c0p);
                sincosf(rope_angle(pos, j1), &s1p, &c1p);
                float pka = __shfl_xor(ka, 16, 64), pkb = __shfl_xor(kb, 16, 64);
                float pva = __shfl_xor(va, 16, 64), pvb = __shfl_xor(vb, 16, 64);
                float koa, kob, voa, vob;
                if (il < 16) {
                    koa = fmaf(ka, c0p, -pka * s0p); kob = fmaf(kb, c1p, -pkb * s1p);
                    voa = fmaf(va, c0p, -pva * s0p); vob = fmaf(vb, c1p, -pvb * s1p);
                } else {
                    koa = fmaf(pka, s0p, ka * c0p);  kob = fmaf(pkb, s1p, kb * c1p);
                    voa = fmaf(pva, s0p, va * c0p);  vob = fmaf(pvb, s1p, vb * c1p);
                }
                size_t off2 = ((size_t)b * KV_LEN + pos) * 64 + 2 * il;
                *(float2*)&Kbuf[off2] = make_float2(koa, kob);
                *(float2*)&Vbuf[off2] = make_float2(voa, vob);
            } else {
                sHdc[tok * 64 + 2 * (l - 32)] = acc[tt][4];
                sHdc[tok * 64 + 2 * (l - 32) + 1] = acc[tt][5];
            }
        }

        __syncthreads();   // sHdc ready; sHT/sW regions now reusable
        for (int i = tid * 4; i < 8192; i += 1024)
            *(float4*)&smem[i] = *(const float4*)(W_IUQ + i);
        if (tid < 64) ((float4*)sWw)[tid] = ((const float4*)W_w)[tid];
        __syncthreads();
        float* sWI = smem;

#pragma unroll
        for (int tt = 0; tt < 4; ++tt) {
            int tok = 4 * tg + tt;
            int bt = bt0 + tok;
            float a0 = 0.f, a1 = 0.f;
#pragma unroll 8
            for (int jj = 0; jj < 64; ++jj) {
                float hv = sHdc[tok * 64 + jj];
                a0 = fmaf(hv, sWI[jj * 128 + l], a0);
                a1 = fmaf(hv, sWI[jj * 128 + 64 + l], a1);
            }
            QI[(size_t)bt * 128 + l] = a0;
            QI[(size_t)bt * 128 + 64 + l] = a1;
            if (l < 4) {
                float aw = 0.f;
                for (int jj = 0; jj < 64; ++jj)
                    aw = fmaf(sHdc[tok * 64 + jj], sWw[jj * 4 + l], aw);
                Wiw[(size_t)bt * 4 + l] = aw;
            }
        }
    } else {
        // ---------------- compress path: 4 comp tokens/block ----------------
        int cid = blockIdx.x - 256;
        int b = cid >> 7;
        int s0 = (cid & 127) * 4;

        float* sA = smem;             // [tt*4+wv][512]: 8192
        float* sRed = smem + 8192;    // [w*4+tt][64]: 1024
        float* sRedI = smem + 9216;   // [w*4+tt][32]: 512

#pragma unroll
        for (int tt = 0; tt < 4; ++tt) {
#pragma unroll
            for (int rl = 0; rl < 2; ++rl) {
                int row = 4 * (s0 + tt) + 2 * wv + rl;
                float4 v = make_float4(0.f, 0.f, 0.f, 0.f);
                if (row < T_DIM)
                    v = *(const float4*)(H + ((size_t)b * T_DIM + row) * 256 + lane * 4);
                *(float4*)&sA[(tt * 4 + wv) * 512 + rl * 256 + lane * 4] = v;
            }
        }
        // each wave reads only its own slices -> no barrier needed

        int k0 = wv * 512;
        float ac[4] = {0.f, 0.f, 0.f, 0.f};
        const float* Wc = Wc_comp + (size_t)k0 * 64 + lane;
        for (int k = 0; k < 512; k += 4) {
            float4 a0 = *(float4*)&sA[(0 * 4 + wv) * 512 + k];
            float4 a1 = *(float4*)&sA[(1 * 4 + wv) * 512 + k];
            float4 a2 = *(float4*)&sA[(2 * 4 + wv) * 512 + k];
            float4 a3 = *(float4*)&sA[(3 * 4 + wv) * 512 + k];
#pragma unroll
            for (int kk = 0; kk < 4; ++kk) {
                float w = Wc[(size_t)(k + kk) * 64];
                ac[0] = fmaf(((const float*)&a0)[kk], w, ac[0]);
                ac[1] = fmaf(((const float*)&a1)[kk], w, ac[1]);
                ac[2] = fmaf(((const float*)&a2)[kk], w, ac[2]);
                ac[3] = fmaf(((const float*)&a3)[kk], w, ac[3]);
            }
        }
#pragma unroll
        for (int tt = 0; tt < 4; ++tt) sRed[(wv * 4 + tt) * 64 + lane] = ac[tt];

        {
            int col = lane & 31;
            int half = lane >> 5;
            float ai[4] = {0.f, 0.f, 0.f, 0.f};
            const float* Wi = Wc_idx + (size_t)k0 * 32 + col;
            int kb = half * 256;
            for (int k = kb; k < kb + 256; k += 4) {
                float4 a0 = *(float4*)&sA[(0 * 4 + wv) * 512 + k];
                float4 a1 = *(float4*)&sA[(1 * 4 + wv) * 512 + k];
                float4 a2 = *(float4*)&sA[(2 * 4 + wv) * 512 + k];
                float4 a3 = *(float4*)&sA[(3 * 4 + wv) * 512 + k];
#pragma unroll
                for (int kk = 0; kk < 4; ++kk) {
                    float w = Wi[(size_t)(k + kk) * 32];
                    ai[0] = fmaf(((const float*)&a0)[kk], w, ai[0]);
                    ai[1] = fmaf(((const float*)&a1)[kk], w, ai[1]);
                    ai[2] = fmaf(((const float*)&a2)[kk], w, ai[2]);
                    ai[3] = fmaf(((const float*)&a3)[kk], w, ai[3]);
                }
            }
#pragma unroll
            for (int tt = 0; tt < 4; ++tt) {
                ai[tt] += __shfl_xor(ai[tt], 32, 64);
                if (lane < 32) sRedI[(wv * 4 + tt) * 32 + lane] = ai[tt];
            }
        }
        __syncthreads();

        // wave wv handles token tt = wv
        {
            int tt = wv;
            int s = s0 + tt;
            float kvv = sRed[(0 * 4 + tt) * 64 + lane] + sRed[(1 * 4 + tt) * 64 + lane] +
                        sRed[(2 * 4 + tt) * 64 + lane] + sRed[(3 * 4 + tt) * 64 + lane];
            float ss = wave_sum64(kvv * kvv);
            float sc = rsqrtf(ss * (1.0f / 64.0f) + 1e-6f);
            float kk = kvv * sc * g_k[lane];
            float vv = kvv * sc * g_v[lane];
            int j = lane & 31;
            float sa, ca;
            sincosf(rope_angle(s, j), &sa, &ca);
            float pk = __shfl_xor(kk, 32, 64);
            float pv = __shfl_xor(vv, 32, 64);
            float ko = (lane < 32) ? fmaf(kk, ca, -pk * sa) : fmaf(pk, sa, kk * ca);
            float vo = (lane < 32) ? fmaf(vv, ca, -pv * sa) : fmaf(pv, sa, vv * ca);
            size_t off = ((size_t)b * KV_LEN + s) * 64 + lane;
            Kbuf[off] = ko;
            Vbuf[off] = vo;
            if (lane < 32) {
                float a = sRedI[(0 * 4 + tt) * 32 + lane] + sRedI[(1 * 4 + tt) * 32 + lane] +
                          sRedI[(2 * 4 + tt) * 32 + lane] + sRedI[(3 * 4 + tt) * 32 + lane];
                KIbuf[((size_t)b * TC + s) * 32 + lane] = a;
            }
        }
    }
}

// ---------------------------------------------------------------------------
// K3: index scores + exact top-8. 4 tokens/block (wave each). KI staged to
// LDS in 64-row chunks (coalesced, pad 33 -> conflict-free), chunks past the
// block's smax skipped (uniform branch).
// ---------------------------------------------------------------------------
__global__ __launch_bounds__(256) void k_score_topk(
    const float* __restrict__ QI, const float* __restrict__ Wiw,
    const float* __restrict__ KIbuf, int* __restrict__ topk)
{
    int tid = threadIdx.x;
    int wv = tid >> 6;
    int lane = tid & 63;
    int bt0 = blockIdx.x * 4;
    int bt = bt0 + wv;
    int b = bt >> 11;
    int t = bt & 2047;

    __shared__ float sQ[4][128];
    __shared__ float sw[4][4];
    __shared__ float sKI[64 * 33];

    sQ[wv][lane] = QI[(size_t)bt * 128 + lane];
    sQ[wv][64 + lane] = QI[(size_t)bt * 128 + 64 + lane];
    if (lane < 4) sw[wv][lane] = Wiw[(size_t)bt * 4 + lane];

    const float* KIb = KIbuf + (size_t)b * TC * 32;
    int smax = t >> 2;
    int smax_blk = ((bt0 + 3) & 2047) >> 2;

    float vals[8];
#pragma unroll
    for (int r = 0; r < 8; ++r) vals[r] = -INFINITY;

    for (int r = 0; r < 8; ++r) {
        if (r * 64 > smax_blk) break;
        __syncthreads();
        for (int i = tid; i < 512; i += 256) {
            int row = i >> 3;
            int cseg = (i & 7) * 4;
            float4 v = *(const float4*)(KIb + (size_t)(r * 64 + row) * 32 + cseg);
            float* dst = &sKI[row * 33 + cseg];
            dst[0] = v.x; dst[1] = v.y; dst[2] = v.z; dst[3] = v.w;
        }
        __syncthreads();

        int s = r * 64 + lane;
        if (s <= smax) {
            float dd0 = 0.f, dd1 = 0.f, dd2 = 0.f, dd3 = 0.f;
#pragma unroll
            for (int c = 0; c < 32; ++c) {
                float kv = sKI[lane * 33 + c];
                dd0 = fmaf(sQ[wv][c], kv, dd0);
                dd1 = fmaf(sQ[wv][32 + c], kv, dd1);
                dd2 = fmaf(sQ[wv][64 + c], kv, dd2);
                dd3 = fmaf(sQ[wv][96 + c], kv, dd3);
            }
            vals[r] = sw[wv][0] * fmaxf(dd0, 0.f) + sw[wv][1] * fmaxf(dd1, 0.f) +
                      sw[wv][2] * fmaxf(dd2, 0.f) + sw[wv][3] * fmaxf(dd3, 0.f);
        }
    }

    unsigned consumed = 0u;
    for (int k2 = 0; k2 < 8; ++k2) {
        float bv = -INFINITY;
        int bi = 0x7fffffff;
#pragma unroll
        for (int r = 0; r < 8; ++r) {
            if (!(consumed & (1u << r))) {
                int s = lane + 64 * r;
                float v = vals[r];
                if (v > bv || (v == bv && s < bi)) { bv = v; bi = s; }
            }
        }
#pragma unroll
        for (int off = 1; off < 64; off <<= 1) {
            float ov = __shfl_xor(bv, off, 64);
            int oi = __shfl_xor(bi, off, 64);
            if (ov > bv || (ov == bv && oi < bi)) { bv = ov; bi = oi; }
        }
        if ((bi & 63) == lane) consumed |= 1u << (bi >> 6);
        if (lane == 0) topk[(size_t)bt * 8 + k2] = bi;
    }
}

// ---------------------------------------------------------------------------
// K4: sparse attention + gates + out. 4 tokens/block (1024 thr, wave/head).
// K and V rows staged once per token into LDS (coalesced, pad 65).
// ---------------------------------------------------------------------------
__global__ __launch_bounds__(1024) void k_attn_out(
    const float* __restrict__ Qr, const float* __restrict__ Kbuf,
    const float* __restrict__ Vbuf, const int* __restrict__ topk,
    const float* __restrict__ Wg0, const float* __restrict__ bg0,
    const float* __restrict__ Wg1, const float* __restrict__ bg1,
    const float* __restrict__ Wout, const float* __restrict__ bout,
    float* __restrict__ out)
{
    int tid = threadIdx.x;
    int lt = tid >> 8;
    int t256 = tid & 255;
    int h = t256 >> 6;
    int lane = tid & 63;
    int bt = blockIdx.x * 4 + lt;
    int b = bt >> 11;
    int t = bt & 2047;

    __shared__ float sKV[4][48 * 65];
    __shared__ float sQ[4][256];
    __shared__ int sPos[4][24];
    __shared__ float sP[4][4][24];
    __shared__ float sO[4][256];
    __shared__ float sPall[4][128];

    sQ[lt][t256] = Qr[(size_t)bt * 256 + t256];
    if (t256 < 8) {
        sPos[lt][t256] = topk[(size_t)bt * 8 + t256];
    } else if (t256 < 24) {
        int rel = t256 - 8;
        int sp = t - rel;
        sPos[lt][t256] = (sp >= 0) ? (TC + sp) : -1;
    }
    __syncthreads();

    for (int i = t256; i < 768; i += 256) {
        int row = i >> 4;
        int seg = (i & 15) << 2;
        int key = (row < 24) ? row : row - 24;
        int pos = sPos[lt][key];
        if (pos >= 0) {
            const float* src = ((row < 24) ? Kbuf : Vbuf) +
                               ((size_t)b * KV_LEN + pos) * 64 + seg;
            float4 v = *(const float4*)src;
            float* dst = &sKV[lt][row * 65 + seg];
            dst[0] = v.x; dst[1] = v.y; dst[2] = v.z; dst[3] = v.w;
        }
    }
    __syncthreads();

    float scv = -INFINITY;
    if (lane < 24) {
        int pos = sPos[lt][lane];
        if (pos >= 0) {
            float dd = 0.f;
#pragma unroll
            for (int c = 0; c < 64; ++c)
                dd = fmaf(sQ[lt][h * 64 + c], sKV[lt][lane * 65 + c], dd);
            scv = dd * 0.125f;
        }
    }
    float m = scv;
#pragma unroll
    for (int off = 1; off < 64; off <<= 1) m = fmaxf(m, __shfl_xor(m, off, 64));
    float p = expf(scv - m);
    if (scv == -INFINITY) p = 0.f;
    float l = p;
#pragma unroll
    for (int off = 1; off < 64; off <<= 1) l += __shfl_xor(l, off, 64);
    p /= l;
    if (lane < 24) sP[lt][h][lane] = p;

    float o = 0.f;
#pragma unroll
    for (int j2 = 0; j2 < 24; ++j2) {
        int pos = sPos[lt][j2];
        if (pos >= 0)
            o = fmaf(sP[lt][h][j2], sKV[lt][(24 + j2) * 65 + lane], o);
    }

    int j = lane & 31;
    float sa, ca;
    sincosf(rope_angle(t, j), &sa, &ca);
    float prt = __shfl_xor(o, 32, 64);
    float oo = (lane < 32) ? fmaf(o, ca, prt * sa) : fmaf(-prt, sa, o * ca);
    sO[lt][h * 64 + lane] = oo;
    __syncthreads();

    if (t256 < 128) {
        float a;
        if (t256 < 64) {
            a = bg0[t256];
            for (int c = 0; c < 128; ++c) a = fmaf(sO[lt][c], Wg0[c * 64 + t256], a);
        } else {
            int i = t256 - 64;
            a = bg1[i];
            for (int c = 0; c < 128; ++c) a = fmaf(sO[lt][128 + c], Wg1[c * 64 + i], a);
        }
        sPall[lt][t256] = a;
    }
    __syncthreads();

    float a = bout[t256];
    for (int i = 0; i < 128; ++i) a = fmaf(sPall[lt][i], Wout[i * 256 + t256], a);
    out[(size_t)bt * 256 + t256] = a;
}

// ---------------------------------------------------------------------------
extern "C" void kernel_launch(void* const* d_in, const int* in_sizes, int n_in,
                              void* d_out, int out_size, void* d_ws, size_t ws_size,
                              hipStream_t stream) {
    const float* H       = (const float*)d_in[0];
    const float* Wc_comp = (const float*)d_in[1];
    const float* Wc_idx  = (const float*)d_in[2];
    const float* W_DQ    = (const float*)d_in[3];
    const float* W_IUQ   = (const float*)d_in[4];
    const float* W_w     = (const float*)d_in[5];
    const float* W_Q     = (const float*)d_in[6];
    const float* W_KV    = (const float*)d_in[7];
    const float* g_q     = (const float*)d_in[8];
    const float* g_k     = (const float*)d_in[9];
    const float* g_v     = (const float*)d_in[10];
    const float* Wg0     = (const float*)d_in[11];
    const float* bg0     = (const float*)d_in[12];
    const float* Wg1     = (const float*)d_in[13];
    const float* bg1     = (const float*)d_in[14];
    const float* Wout    = (const float*)d_in[15];
    const float* bout    = (const float*)d_in[16];

    float* ws  = (float*)d_ws;
    float* QI  = ws;                  // B*T*128   = 524288
    float* Qr  = QI + 524288;         // B*T*256   = 1048576
    float* Wiw = Qr + 1048576;        // B*T*4     = 16384
    float* KI  = Wiw + 16384;         // B*TC*32   = 32768
    float* Kb  = KI + 32768;          // B*2560*64 = 327680
    float* Vb  = Kb + 327680;         // B*2560*64 = 327680
    int* topkb = (int*)(Vb + 327680); // B*T*8

    float* outp = (float*)d_out;

    hipLaunchKernelGGL(k_phase1, dim3(512), dim3(256), 0, stream,
                       H, W_Q, W_KV, W_DQ, W_IUQ, W_w, Wc_comp, Wc_idx,
                       g_q, g_k, g_v, QI, Wiw, Qr, KI, Kb, Vb);
    hipLaunchKernelGGL(k_score_topk, dim3((B_DIM * T_DIM) / 4), dim3(256), 0, stream,
                       QI, Wiw, KI, topkb);
    hipLaunchKernelGGL(k_attn_out, dim3((B_DIM * T_DIM) / 4), dim3(1024), 0, stream,
                       Qr, Kb, Vb, topkb, Wg0, bg0, Wg1, bg1, Wout, bout, outp);
}